// Round 1
// baseline (17626.010 us; speedup 1.0000x reference)
//
#include <hip/hip_runtime.h>

#define T_STEPS 512
#define DK 512       // D == H == 512
#define NC 2048      // 4H

static __device__ __forceinline__ float bf2f(unsigned short u) {
    return __uint_as_float(((unsigned int)u) << 16);
}
static __device__ __forceinline__ unsigned short f2bf(float f) {
    unsigned int u = __float_as_uint(f);
    u += 0x7fffu + ((u >> 16) & 1u);
    return (unsigned short)(u >> 16);
}
static __device__ __forceinline__ float sigmoidf_(float x) {
    return 1.0f / (1.0f + __expf(-x));
}
static __device__ __forceinline__ float tanhf_(float x) {
    return 1.0f - 2.0f / (__expf(2.0f * x) + 1.0f);
}

// ---------------------------------------------------------------------------
// K1: xW[m][c] = sum_k x[m][k] * Wx[k][c] + b[c]
// M = 32768 (=N*T), K = 512, N = 2048. 64x64 tile, BK=16, 256 thr, 4x4/thread.
// ---------------------------------------------------------------------------
template <bool BF16OUT>
__global__ __launch_bounds__(256)
void gemm_xw(const float* __restrict__ x, const float* __restrict__ Wx,
             const float* __restrict__ bias, void* __restrict__ xw_out) {
    __shared__ float As[16][68];   // [k][row], +4 pad keeps 16B align, breaks conflicts
    __shared__ float Bs[16][64];   // [k][col]
    const int tid  = threadIdx.x;
    const int tx   = tid & 15;
    const int ty   = tid >> 4;
    const int row0 = blockIdx.x * 64;
    const int col0 = blockIdx.y * 64;

    const int ar = tid >> 2;          // A-load row 0..63
    const int ak = (tid & 3) << 2;    // A-load k   0,4,8,12
    const int bk = tid >> 4;          // B-load k   0..15
    const int bc = (tid & 15) << 2;   // B-load col 0..60

    float acc[4][4] = {};

    for (int k0 = 0; k0 < DK; k0 += 16) {
        const float4 av = *(const float4*)(x  + (size_t)(row0 + ar) * DK + k0 + ak);
        const float4 bv = *(const float4*)(Wx + (size_t)(k0 + bk) * NC + col0 + bc);
        __syncthreads();   // previous iteration's LDS readers done
        As[ak + 0][ar] = av.x;
        As[ak + 1][ar] = av.y;
        As[ak + 2][ar] = av.z;
        As[ak + 3][ar] = av.w;
        *(float4*)&Bs[bk][bc] = bv;
        __syncthreads();
        #pragma unroll
        for (int k = 0; k < 16; ++k) {
            float a4[4], b4[4];
            *(float4*)a4 = *(const float4*)&As[k][ty << 2];
            *(float4*)b4 = *(const float4*)&Bs[k][tx << 2];
            #pragma unroll
            for (int i = 0; i < 4; ++i)
                #pragma unroll
                for (int j = 0; j < 4; ++j)
                    acc[i][j] += a4[i] * b4[j];
        }
    }

    #pragma unroll
    for (int i = 0; i < 4; ++i) {
        const size_t row = (size_t)row0 + (ty << 2) + i;
        const int    col = col0 + (tx << 2);
        float v[4];
        #pragma unroll
        for (int j = 0; j < 4; ++j) v[j] = acc[i][j] + bias[col + j];
        if (BF16OUT) {
            ushort4 s;
            s.x = f2bf(v[0]); s.y = f2bf(v[1]); s.z = f2bf(v[2]); s.w = f2bf(v[3]);
            *(ushort4*)((unsigned short*)xw_out + row * NC + col) = s;
        } else {
            *(float4*)((float*)xw_out + row * NC + col) = *(float4*)v;
        }
    }
}

// ---------------------------------------------------------------------------
// K2: per-batch recurrent chain. One WG per batch element, 512 threads.
// h,c,a live in LDS; Wh streamed from L2 (4 MB, resident). No grid sync.
// Thread tid owns cols 4*tid..4*tid+3 of a (all four gates covered across
// threads); gate phase: thread tid owns hidden unit tid.
// ---------------------------------------------------------------------------
template <bool XW_BF16>
__global__ __launch_bounds__(512)
void lstm_rec(const void* __restrict__ xw, const float* __restrict__ Wh,
              const float* __restrict__ h0, float* __restrict__ out) {
    __shared__ float h_s[DK];
    __shared__ float c_s[DK];
    __shared__ float a_s[NC];
    const int b   = blockIdx.x;       // batch element
    const int tid = threadIdx.x;      // 0..511
    const int q   = tid << 2;         // col base in [0,2048)

    h_s[tid] = h0[(size_t)b * DK + tid];
    c_s[tid] = 0.0f;
    __syncthreads();

    for (int t = 0; t < T_STEPS; ++t) {
        const size_t rowoff = ((size_t)b * T_STEPS + t) * NC;
        float4 acc;
        if (XW_BF16) {
            const ushort4 xv = *(const ushort4*)((const unsigned short*)xw + rowoff + q);
            acc.x = bf2f(xv.x); acc.y = bf2f(xv.y);
            acc.z = bf2f(xv.z); acc.w = bf2f(xv.w);
        } else {
            acc = *(const float4*)((const float*)xw + rowoff + q);
        }
        const float* wp = Wh + q;
        #pragma unroll 4
        for (int k = 0; k < DK; k += 4) {
            const float4 hk = *(const float4*)&h_s[k];
            const float4 w0 = *(const float4*)(wp + (size_t)(k + 0) * NC);
            const float4 w1 = *(const float4*)(wp + (size_t)(k + 1) * NC);
            const float4 w2 = *(const float4*)(wp + (size_t)(k + 2) * NC);
            const float4 w3 = *(const float4*)(wp + (size_t)(k + 3) * NC);
            acc.x += hk.x * w0.x + hk.y * w1.x + hk.z * w2.x + hk.w * w3.x;
            acc.y += hk.x * w0.y + hk.y * w1.y + hk.z * w2.y + hk.w * w3.y;
            acc.z += hk.x * w0.z + hk.y * w1.z + hk.z * w2.z + hk.w * w3.z;
            acc.w += hk.x * w0.w + hk.y * w1.w + hk.z * w2.w + hk.w * w3.w;
        }
        *(float4*)&a_s[q] = acc;
        __syncthreads();   // a complete; all h_s reads for this step done

        // gates for hidden unit u = tid:  i=a[u], f=a[512+u], o=a[1024+u], g=a[1536+u]
        const float ig = sigmoidf_(a_s[tid]);
        const float fg = sigmoidf_(a_s[DK + tid]);
        const float og = sigmoidf_(a_s[2 * DK + tid]);
        const float gg = tanhf_(a_s[3 * DK + tid]);
        const float c  = fg * c_s[tid] + ig * gg;
        const float h  = og * tanhf_(c);
        c_s[tid] = c;
        h_s[tid] = h;                                   // safe: no h_s readers now
        out[((size_t)b * T_STEPS + t) * DK + tid] = h;  // coalesced
        __syncthreads();   // h_s/a_s stable before next step
    }
}

// ---------------------------------------------------------------------------
extern "C" void kernel_launch(void* const* d_in, const int* in_sizes, int n_in,
                              void* d_out, int out_size, void* d_ws, size_t ws_size,
                              hipStream_t stream) {
    const float* x    = (const float*)d_in[0];
    const float* h0   = (const float*)d_in[1];
    const float* Wx   = (const float*)d_in[2];
    const float* Wh   = (const float*)d_in[3];
    const float* bias = (const float*)d_in[4];
    float* out = (float*)d_out;

    const size_t xw_f32_bytes = (size_t)64 * T_STEPS * NC * sizeof(float); // 268 MB
    const bool use_f32 = (ws_size >= xw_f32_bytes);

    dim3 g1(512, 32);   // 32768/64 M-tiles x 2048/64 N-tiles
    if (use_f32) {
        gemm_xw<false><<<g1, 256, 0, stream>>>(x, Wx, bias, d_ws);
        lstm_rec<false><<<64, 512, 0, stream>>>(d_ws, Wh, h0, out);
    } else {
        gemm_xw<true><<<g1, 256, 0, stream>>>(x, Wx, bias, d_ws);
        lstm_rec<true><<<64, 512, 0, stream>>>(d_ws, Wh, h0, out);
    }
}

// Round 2
// 11377.354 us; speedup vs baseline: 1.5492x; 1.5492x over previous
//
#include <hip/hip_runtime.h>

#define TSTEPS 512
#define DK 512       // D == H == 512
#define NC 2048      // 4H
#define NWG 128      // recurrent workgroups
#define WGT 256

typedef unsigned int u32;
typedef unsigned short u16;

static __device__ __forceinline__ float bf2f(u16 u) {
    return __uint_as_float(((u32)u) << 16);
}
static __device__ __forceinline__ u16 f2bf(float f) {
    u32 u = __float_as_uint(f);
    u += 0x7fffu + ((u >> 16) & 1u);
    return (u16)(u >> 16);
}
static __device__ __forceinline__ float sigmoidf_(float x) { return 1.0f / (1.0f + __expf(-x)); }
static __device__ __forceinline__ float tanhf_(float x)    { return 1.0f - 2.0f / (__expf(2.0f * x) + 1.0f); }

// ---------------------------------------------------------------------------
// K1: xW[m][c] = sum_k x[m][k]*Wx[k][c] + b[c], bf16 output.
// M=32768, K=512, N=2048. 64x64 tile, BK=16, 256 thr, 4x4/thread.
// ---------------------------------------------------------------------------
__global__ __launch_bounds__(256)
void gemm_xw(const float* __restrict__ x, const float* __restrict__ Wx,
             const float* __restrict__ bias, u16* __restrict__ xw_out) {
    __shared__ float As[16][68];
    __shared__ float Bs[16][64];
    const int tid  = threadIdx.x;
    const int tx   = tid & 15;
    const int ty   = tid >> 4;
    const int row0 = blockIdx.x * 64;
    const int col0 = blockIdx.y * 64;

    const int ar = tid >> 2;
    const int ak = (tid & 3) << 2;
    const int bk = tid >> 4;
    const int bc = (tid & 15) << 2;

    float acc[4][4] = {};

    for (int k0 = 0; k0 < DK; k0 += 16) {
        const float4 av = *(const float4*)(x  + (size_t)(row0 + ar) * DK + k0 + ak);
        const float4 bv = *(const float4*)(Wx + (size_t)(k0 + bk) * NC + col0 + bc);
        __syncthreads();
        As[ak + 0][ar] = av.x;
        As[ak + 1][ar] = av.y;
        As[ak + 2][ar] = av.z;
        As[ak + 3][ar] = av.w;
        *(float4*)&Bs[bk][bc] = bv;
        __syncthreads();
        #pragma unroll
        for (int k = 0; k < 16; ++k) {
            float a4[4], b4[4];
            *(float4*)a4 = *(const float4*)&As[k][ty << 2];
            *(float4*)b4 = *(const float4*)&Bs[k][tx << 2];
            #pragma unroll
            for (int i = 0; i < 4; ++i)
                #pragma unroll
                for (int j = 0; j < 4; ++j)
                    acc[i][j] += a4[i] * b4[j];
        }
    }

    #pragma unroll
    for (int i = 0; i < 4; ++i) {
        const size_t row = (size_t)row0 + (ty << 2) + i;
        const int    col = col0 + (tx << 2);
        ushort4 s;
        s.x = f2bf(acc[i][0] + bias[col + 0]);
        s.y = f2bf(acc[i][1] + bias[col + 1]);
        s.z = f2bf(acc[i][2] + bias[col + 2]);
        s.w = f2bf(acc[i][3] + bias[col + 3]);
        *(ushort4*)(xw_out + row * NC + col) = s;
    }
}

// ---------------------------------------------------------------------------
// Round-1 fallback recurrent kernel (used only if ws too small): one WG per
// batch element, Wh streamed from L2 (per-CU L2-BW bound, ~16.8 ms).
// ---------------------------------------------------------------------------
__global__ __launch_bounds__(512)
void lstm_rec_old(const u16* __restrict__ xw, const float* __restrict__ Wh,
                  const float* __restrict__ h0, float* __restrict__ out) {
    __shared__ float h_s[DK];
    __shared__ float c_s[DK];
    __shared__ float a_s[NC];
    const int b   = blockIdx.x;
    const int tid = threadIdx.x;
    const int q   = tid << 2;

    h_s[tid] = h0[(size_t)b * DK + tid];
    c_s[tid] = 0.0f;
    __syncthreads();

    for (int t = 0; t < TSTEPS; ++t) {
        const size_t rowoff = ((size_t)b * TSTEPS + t) * NC;
        const ushort4 xv = *(const ushort4*)(xw + rowoff + q);
        float4 acc;
        acc.x = bf2f(xv.x); acc.y = bf2f(xv.y); acc.z = bf2f(xv.z); acc.w = bf2f(xv.w);
        const float* wp = Wh + q;
        #pragma unroll 4
        for (int k = 0; k < DK; k += 4) {
            const float4 hk = *(const float4*)&h_s[k];
            const float4 w0 = *(const float4*)(wp + (size_t)(k + 0) * NC);
            const float4 w1 = *(const float4*)(wp + (size_t)(k + 1) * NC);
            const float4 w2 = *(const float4*)(wp + (size_t)(k + 2) * NC);
            const float4 w3 = *(const float4*)(wp + (size_t)(k + 3) * NC);
            acc.x += hk.x * w0.x + hk.y * w1.x + hk.z * w2.x + hk.w * w3.x;
            acc.y += hk.x * w0.y + hk.y * w1.y + hk.z * w2.y + hk.w * w3.y;
            acc.z += hk.x * w0.z + hk.y * w1.z + hk.z * w2.z + hk.w * w3.z;
            acc.w += hk.x * w0.w + hk.y * w1.w + hk.z * w2.w + hk.w * w3.w;
        }
        *(float4*)&a_s[q] = acc;
        __syncthreads();
        const float ig = sigmoidf_(a_s[tid]);
        const float fg = sigmoidf_(a_s[DK + tid]);
        const float og = sigmoidf_(a_s[2 * DK + tid]);
        const float gg = tanhf_(a_s[3 * DK + tid]);
        const float c  = fg * c_s[tid] + ig * gg;
        const float h  = og * tanhf_(c);
        c_s[tid] = c;
        h_s[tid] = h;
        out[((size_t)b * TSTEPS + t) * DK + tid] = h;
        __syncthreads();
    }
}

// ---------------------------------------------------------------------------
// Counter init (ws is poisoned 0xAA before every launch).
// ---------------------------------------------------------------------------
__global__ void init_cnt(u32* cnt) {
    const int i = threadIdx.x;
    if (i < 4) cnt[i * 16] = 0u;
}

// ---------------------------------------------------------------------------
// K2 (new): LDS-resident Wh, 128 WGs x 256 thr. Wave w of WG g owns hidden
// unit u=4g+w (its 4 gate columns of Wh live in LDS, loaded once). Lane =
// batch index (wave size 64 == batch 64). Each step: stage full h(t) from
// global h_buf (double-buffered) into LDS in 4x32KB chunks gated by 4
// agent-scope counters (32 WGs each); 4 dot-512s per lane; gates in regs
// (c persists in a VGPR across all 512 steps); publish h slice.
// Chunk gating gives max 1-step skew; all 128 WGs co-resident (64KB LDS ->
// 1 WG/CU, 128 <= 256 CUs) so spinning cannot deadlock.
// ---------------------------------------------------------------------------
__global__ __launch_bounds__(WGT, 1)
void lstm_rec2(const u16* __restrict__ xw, const float* __restrict__ Wh,
               const float* __restrict__ h0, float* __restrict__ out,
               float* __restrict__ h_buf, u32* __restrict__ cnt) {
    __shared__ float wh_s[4][4][DK];   // [wave][gate][k]  32 KB
    __shared__ float h_s[128 * 64];    // h chunk [k][b]   32 KB (reused as h-transpose buf)
    const int tid = threadIdx.x;
    const int b   = tid & 63;                                  // batch index
    const int wv  = __builtin_amdgcn_readfirstlane(tid >> 6);  // wave id (uniform)
    const int g   = blockIdx.x;
    const int u   = 4 * g + wv;                                // hidden unit
    const int grp = g >> 5;                                    // counter group

    // Preload Wh slice: wh_s[wv][j][k] = Wh[k][j*512+u]  (once; scattered but tiny)
    for (int j = 0; j < 4; ++j)
        for (int k = b; k < DK; k += 64)
            wh_s[wv][j][k] = Wh[(size_t)k * NC + j * 512 + u];

    // h0 -> h_buf[0] in transposed [u][b] layout
    h_buf[u * 64 + b] = h0[(size_t)b * DK + u];
    float creg = 0.0f;
    __syncthreads();
    if (tid == 0)
        __hip_atomic_fetch_add(&cnt[grp * 16], 1u, __ATOMIC_RELEASE, __HIP_MEMORY_SCOPE_AGENT);

    for (int t = 0; t < TSTEPS; ++t) {
        // xw prefetch (4 gate cols for (b,t)); volatile pins early issue so the
        // ~900cy HBM latency hides behind spin+stage+gemm.
        const volatile u16* xp = xw + ((size_t)b * TSTEPS + t) * NC + u;
        const u16 x0 = xp[0], x1 = xp[512], x2 = xp[1024], x3 = xp[1536];

        const float* hb_cur = h_buf + (size_t)(t & 1) * (DK * 64);
        float acc0 = 0.f, acc1 = 0.f, acc2 = 0.f, acc3 = 0.f;
        const u32 target = 32u * (u32)(t + 1);

        for (int c = 0; c < 4; ++c) {
            if (tid == 0) {
                // acquire: also invalidates L1/L2 so staged h is fresh cross-XCD
                while (__hip_atomic_fetch_add(&cnt[c * 16], 0u, __ATOMIC_ACQUIRE,
                                              __HIP_MEMORY_SCOPE_AGENT) < target)
                    __builtin_amdgcn_s_sleep(1);
            }
            __syncthreads();
            // stage 32 KB chunk (128 k-rows x 64 b), coalesced float4
            const float4* src = (const float4*)(hb_cur + c * (128 * 64));
            float4* dst = (float4*)h_s;
            #pragma unroll
            for (int i = 0; i < 8; ++i) dst[tid + WGT * i] = src[tid + WGT * i];
            __syncthreads();

            const float* whp0 = &wh_s[wv][0][c * 128];
            const float* whp1 = &wh_s[wv][1][c * 128];
            const float* whp2 = &wh_s[wv][2][c * 128];
            const float* whp3 = &wh_s[wv][3][c * 128];
            #pragma unroll 4
            for (int k = 0; k < 128; k += 4) {
                const float4 w0 = *(const float4*)(whp0 + k);   // LDS b128 broadcast
                const float4 w1 = *(const float4*)(whp1 + k);
                const float4 w2 = *(const float4*)(whp2 + k);
                const float4 w3 = *(const float4*)(whp3 + k);
                const float hv0 = h_s[(k + 0) * 64 + b];        // ds_b32, conflict-free
                const float hv1 = h_s[(k + 1) * 64 + b];
                const float hv2 = h_s[(k + 2) * 64 + b];
                const float hv3 = h_s[(k + 3) * 64 + b];
                acc0 += hv0 * w0.x + hv1 * w0.y + hv2 * w0.z + hv3 * w0.w;
                acc1 += hv0 * w1.x + hv1 * w1.y + hv2 * w1.z + hv3 * w1.w;
                acc2 += hv0 * w2.x + hv1 * w2.y + hv2 * w2.z + hv3 * w2.w;
                acc3 += hv0 * w3.x + hv1 * w3.y + hv2 * w3.z + hv3 * w3.w;
            }
        }

        // gates (c stays in a register across all 512 steps)
        const float ig = sigmoidf_(acc0 + bf2f(x0));
        const float fg = sigmoidf_(acc1 + bf2f(x1));
        const float og = sigmoidf_(acc2 + bf2f(x2));
        const float gg = tanhf_  (acc3 + bf2f(x3));
        creg = fg * creg + ig * gg;
        const float hnew = og * tanhf_(creg);

        float* hb_nxt = h_buf + (size_t)((t + 1) & 1) * (DK * 64);
        __syncthreads();                 // E1: all h_s reads done before reuse
        hb_nxt[u * 64 + b] = hnew;       // coalesced 256B/wave
        h_s[wv * 64 + b] = hnew;         // stage for out-transpose
        __syncthreads();                 // E2: h_buf stores drained, h_s ready
        if (wv == 0) {
            float4 o4;
            o4.x = h_s[b]; o4.y = h_s[64 + b]; o4.z = h_s[128 + b]; o4.w = h_s[192 + b];
            *(float4*)(out + ((size_t)b * TSTEPS + t) * DK + 4 * g) = o4;
        }
        if (tid == 0)
            __hip_atomic_fetch_add(&cnt[grp * 16], 1u, __ATOMIC_RELEASE, __HIP_MEMORY_SCOPE_AGENT);
    }
}

// ---------------------------------------------------------------------------
extern "C" void kernel_launch(void* const* d_in, const int* in_sizes, int n_in,
                              void* d_out, int out_size, void* d_ws, size_t ws_size,
                              hipStream_t stream) {
    const float* x    = (const float*)d_in[0];
    const float* h0   = (const float*)d_in[1];
    const float* Wx   = (const float*)d_in[2];
    const float* Wh   = (const float*)d_in[3];
    const float* bias = (const float*)d_in[4];
    float* out = (float*)d_out;

    u16* xw = (u16*)d_ws;
    const size_t XW_BYTES = (size_t)64 * TSTEPS * NC * sizeof(u16);   // 134217728
    float* h_buf = (float*)((char*)d_ws + XW_BYTES);                  // 2*512*64 f32
    u32*   cnt   = (u32*)((char*)d_ws + XW_BYTES + 262144);           // 4 ctrs, 64B apart
    const size_t need = XW_BYTES + 262144 + 256;

    dim3 g1(512, 32);   // 32768/64 x 2048/64
    gemm_xw<<<g1, 256, 0, stream>>>(x, Wx, bias, xw);
    if (ws_size >= need) {
        init_cnt<<<1, 64, 0, stream>>>(cnt);
        lstm_rec2<<<NWG, WGT, 0, stream>>>(xw, Wh, h0, out, h_buf, cnt);
    } else {
        lstm_rec_old<<<64, 512, 0, stream>>>(xw, Wh, h0, out);
    }
}